// Round 9
// baseline (207.504 us; speedup 1.0000x reference)
//
#include <hip/hip_runtime.h>
#include <math.h>

#define NC 100
#define ND 384
#define NB 4096
#define KS 8                         // dim-split: 8 ks per mb-group
#define KT 48
#define MT 128                       // samples per gemm block
#define XSP 52                       // xs row pad (13 float4)
#define CLS_PAD 132                  // d-major class row pad (16B-aligned b128)
#define PPR 100                      // partial row (NC floats, 400 B, 16B-aligned)
#define GRID 256                     // 32 mb-groups x 8 ks = 1 block/CU
// done-counter target: poison (0xAAAAAAAA documented) + 256 gemm + 100 cdist
#define DONE_TARGET (0xAAAAAAAAu + 356u)
#define SAF (MT * XSP + 2 * KT * CLS_PAD + 112)  // 19440 floats = 77.8 KB

// ONE kernel, 256 blocks (mb=b>>3, ks=b&7):
//  all blocks: gemm partials (incl. w*c^2 term) -> fence -> done++
//  blocks 0..99: then cdist[class b] -> fence -> done++
//  blocks ks==7: then presence mask (VGPR+LDS tree, no atomics), ONE thread
//    politely polls `done` (relaxed device loads + s_sleep) until all 356
//    increments, then finishes its 128 samples -> one atomicAdd.
//  Deadlock-free: grid 256 = 1 block/CU, everything resident; finishers
//  increment before they wait.
__global__ __launch_bounds__(256, 2) void fused_all(
    const float* __restrict__ x, const int* __restrict__ targets,
    const float* __restrict__ centers, const float* __restrict__ cw,
    float* __restrict__ cdist, unsigned* __restrict__ done,
    float* __restrict__ part, float* __restrict__ out) {
  __shared__ float sA[SAF];
  int b = blockIdx.x, tid = threadIdx.x;
  int wave = tid >> 6, lane = tid & 63;
  int mb = b >> 3, ks = b & 7;
  int koff = ks * KT;

  // ================= phase 1: gemm (all 256 blocks) =================
  {
    float* xs = sA;                      // [128][52]
    float* ws_t = sA + MT * XSP;         // [48][132] d-major: w
    float* as_t = ws_t + KT * CLS_PAD;   // [48][132] d-major: -2*w*c
    float* ts = as_t + KT * CLS_PAD;     // [100] per-class sum_d w*c^2 (block dims)

    if (b == 0 && tid == 255) out[0] = 0.f;  // covered by fence before done++

    #pragma unroll
    for (int r = 0; r < 8; r++) {        // xs: 128 rows x 12 float4
      int idx = tid + 256 * r;
      int row = idx >> 4, slot = idx & 15;
      if (slot < 12) {
        float4 v = *(const float4*)(x + (mb * MT + row) * ND + koff + 4 * slot);
        *(float4*)&xs[row * XSP + 4 * slot] = v;
      }
    }
    for (int r = 0; r < 19; r++) {       // class data: coalesced read, d-major write
      int idx = tid + 256 * r;
      if (idx < NC * KT) {
        int k = idx / KT, d = idx - k * KT;
        float w = exp2f(cw[k * ND + koff + d]);
        float c = centers[k * ND + koff + d];
        ws_t[d * CLS_PAD + k] = w;
        as_t[d * CLS_PAD + k] = -2.f * w * c;
      }
    }
    __syncthreads();
    if (tid < NC) {                      // ts[k] = sum_d w*c^2 = sum as^2/(4w)
      float s = 0.f;
      for (int d = 0; d < KT; d++) {
        float av = as_t[d * CLS_PAD + tid];
        float wv = ws_t[d * CLS_PAD + tid];
        s += 0.25f * av * av / wv;
      }
      ts[tid] = s;
    }

    int cg = tid & 31, sg = tid >> 5;    // classes 4cg..4cg+3; samples sg+8m
    float acc[16][4];
    #pragma unroll
    for (int m = 0; m < 16; m++)
      #pragma unroll
      for (int u = 0; u < 4; u++) acc[m][u] = 0.f;

    #pragma unroll 1
    for (int d4 = 0; d4 < KT; d4 += 4) {
      float wv[4][4], av[4][4], xv[16][4];
      #pragma unroll
      for (int i2 = 0; i2 < 4; i2++) {
        *(float4*)&wv[i2][0] = *(const float4*)&ws_t[(d4 + i2) * CLS_PAD + 4 * cg];
        *(float4*)&av[i2][0] = *(const float4*)&as_t[(d4 + i2) * CLS_PAD + 4 * cg];
      }
      #pragma unroll
      for (int m = 0; m < 16; m++)
        *(float4*)&xv[m][0] = *(const float4*)&xs[(sg + 8 * m) * XSP + d4];
      #pragma unroll
      for (int i2 = 0; i2 < 4; i2++) {
        #pragma unroll
        for (int m = 0; m < 16; m++) {
          float xval = xv[m][i2];
          #pragma unroll
          for (int u = 0; u < 4; u++)
            acc[m][u] = fmaf(xval, fmaf(xval, wv[i2][u], av[i2][u]), acc[m][u]);
        }
      }
    }
    __syncthreads();                     // ts ready
    if (cg < 25) {
      float4 t4 = *(float4*)&ts[4 * cg];
      #pragma unroll
      for (int m = 0; m < 16; m++) {
        int i = mb * MT + sg + 8 * m;
        float4 v;
        v.x = acc[m][0] + t4.x; v.y = acc[m][1] + t4.y;
        v.z = acc[m][2] + t4.z; v.w = acc[m][3] + t4.w;
        *(float4*)&part[(ks * NB + i) * PPR + 4 * cg] = v;
      }
    }
    __threadfence();                     // release partials (+ out[0] for b==0)
    __syncthreads();
    if (tid == 0) atomicAdd(done, 1u);
  }

  // ================= phase 2: cdist (blocks 0..99) =================
  if (b < NC) {
    int i = b;
    __syncthreads();                     // re-purpose sA
    float* ci_s = sA;
    float* wi_s = sA + ND;
    float* sred = sA + 2 * ND;
    for (int d = tid; d < ND; d += 256) {
      ci_s[d] = centers[i * ND + d];
      wi_s[d] = exp2f(cw[i * ND + d]);
    }
    __syncthreads();
    float minv = 1e30f;
    for (int s4 = 0; s4 < 24; s4 += 4) { // wave handles j = wave + 4*s
      float red[4];
      #pragma unroll
      for (int u = 0; u < 4; u++) {
        int j = wave + 4 * (s4 + u);
        float acc = 0.f;
        #pragma unroll
        for (int e = 0; e < 6; e++) {
          int d = lane + 64 * e;
          float df = ci_s[d] - centers[j * ND + d];
          acc = fmaf(wi_s[d] * df, df, acc);
        }
        red[u] = acc;
      }
      #pragma unroll
      for (int off = 32; off; off >>= 1) {
        #pragma unroll
        for (int u = 0; u < 4; u++) red[u] += __shfl_xor(red[u], off, 64);
      }
      #pragma unroll
      for (int u = 0; u < 4; u++) {
        int j = wave + 4 * (s4 + u);
        if (j != i) minv = fminf(minv, red[u]);
      }
    }
    {  // tail j = wave + 96
      int j = wave + 96;
      float acc = 0.f;
      #pragma unroll
      for (int e = 0; e < 6; e++) {
        int d = lane + 64 * e;
        float df = ci_s[d] - centers[j * ND + d];
        acc = fmaf(wi_s[d] * df, df, acc);
      }
      #pragma unroll
      for (int off = 32; off; off >>= 1) acc += __shfl_xor(acc, off, 64);
      if (j != i) minv = fminf(minv, acc);
    }
    if (lane == 0) sred[wave] = minv;
    __syncthreads();
    if (tid == 0)
      cdist[i] = sqrtf(fminf(fminf(sred[0], sred[1]), fminf(sred[2], sred[3])));
    __threadfence();                     // release cdist[i]
    __syncthreads();
    if (tid == 0) atomicAdd(done, 1u);
  }

  // ================= phase 3: finish (blocks ks==7) =================
  if (ks == 7) {
    unsigned* sAu = (unsigned*)sA;       // [256][5] + [4] final mask
    __syncthreads();
    // presence mask: per-thread VGPR masks, stride-5 LDS tree (no atomics)
    unsigned m0 = 0, m1 = 0, m2 = 0, m3 = 0;
    #pragma unroll
    for (int r = 0; r < 16; r++) {
      int t = targets[tid + 256 * r];
      unsigned bit = 1u << (t & 31);
      if (t < 32) m0 |= bit;
      else if (t < 64) m1 |= bit;
      else if (t < 96) m2 |= bit;
      else m3 |= bit;
    }
    sAu[tid * 5 + 0] = m0; sAu[tid * 5 + 1] = m1;
    sAu[tid * 5 + 2] = m2; sAu[tid * 5 + 3] = m3;
    __syncthreads();
    if (wave < 4) {                      // wave w reduces word w over 256 rows
      unsigned v = sAu[lane * 5 + wave] | sAu[(lane + 64) * 5 + wave] |
                   sAu[(lane + 128) * 5 + wave] | sAu[(lane + 192) * 5 + wave];
      #pragma unroll
      for (int off = 32; off; off >>= 1) v |= __shfl_xor(v, off, 64);
      if (lane == 0) sAu[1280 + wave] = v;
    }
    // ---- gentle poll: ONE thread, relaxed device loads + sleep ----
    if (tid == 0) {
      while (__hip_atomic_load(done, __ATOMIC_RELAXED,
                               __HIP_MEMORY_SCOPE_AGENT) != DONE_TARGET)
        __builtin_amdgcn_s_sleep(2);
    }
    __syncthreads();
    __threadfence();                     // acquire before reading partials/cdist

    unsigned msk[4] = {sAu[1280], sAu[1281], sAu[1282], sAu[1283]};
    float* ls = (float*)&sAu[1288];
    int i = mb * MT + (tid >> 1);        // 2 threads per sample
    int h = tid & 1;                     // class-quad halves: 13 + 12
    int ti = targets[i];
    float cc = cdist[ti];
    float an = 1e30f, ap = 0.f;
    int kq0 = h ? 13 : 0, kq1 = h ? 25 : 13;
    for (int kq = kq0; kq < kq1; kq++) {
      float4 d2 = make_float4(0.f, 0.f, 0.f, 0.f);
      #pragma unroll
      for (int s = 0; s < KS; s++) {
        float4 p = *(const float4*)(part + (s * NB + i) * PPR + 4 * kq);
        d2.x += p.x; d2.y += p.y; d2.z += p.z; d2.w += p.w;
      }
      float dd[4] = {d2.x, d2.y, d2.z, d2.w};
      #pragma unroll
      for (int j = 0; j < 4; j++) {
        int k = 4 * kq + j;
        float dist = sqrtf(fmaxf(dd[j], 1e-12f));
        bool pres = (msk[k >> 5] >> (k & 31)) & 1u;
        if (k == ti) ap = dist;
        else if (pres) an = fminf(an, dist);
      }
    }
    an = fminf(an, __shfl_xor(an, 1, 64));   // merge the h-pair
    ap = fmaxf(ap, __shfl_xor(ap, 1, 64));
    float loss = ap + ((an >= cc) ? 0.f : cc - an);
    #pragma unroll
    for (int off = 32; off; off >>= 1) loss += __shfl_xor(loss, off, 64);
    if (lane == 0) ls[wave] = loss;
    __syncthreads();
    if (tid == 0) {
      float tsum = (ls[0] + ls[1] + ls[2] + ls[3]) * 0.5f;  // pair double-count
      atomicAdd(out, tsum * (1.0f / NB));
    }
  }
}

extern "C" void kernel_launch(void* const* d_in, const int* in_sizes, int n_in,
                              void* d_out, int out_size, void* d_ws, size_t ws_size,
                              hipStream_t stream) {
  const float* inputs  = (const float*)d_in[0];
  const int*   targets = (const int*)d_in[1];
  // d_in[2] = epoch_number (unused by the reference math)
  const float* centers = (const float*)d_in[3];
  const float* cw      = (const float*)d_in[4];
  float* out = (float*)d_out;

  float* cdist    = (float*)d_ws;                // [128]
  unsigned* done  = (unsigned*)(cdist + 128);    // [1]; poison 0xAAAAAAAA is the base
  float* part     = (float*)(done + 32);         // [8*4096*100] = 13.1 MB

  fused_all<<<GRID, 256, 0, stream>>>(inputs, targets, centers, cw, cdist,
                                      done, part, out);
}

// Round 10
// 92.843 us; speedup vs baseline: 2.2350x; 2.2350x over previous
//
#include <hip/hip_runtime.h>
#include <math.h>

#define NC 100
#define ND 384
#define NB 4096
#define KS 8                        // K-split: 8 blocks of 48 dims
#define KT 48                       // dims per gemm block
#define MT 128                      // samples per gemm block
#define XSP 52                      // xs row pad (13 float4, 16B-aligned)
#define CLS_PAD 132                 // d-major class row pad (16B-aligned b128 reads)
#define PPAD 104                    // partial row pad
#define AUX 116                     // 100 cdist/tcc + 16 presence
#define GEMM_BLOCKS ((NB / MT) * KS)  // 256
#define SAF (MT * XSP + 2 * KT * CLS_PAD)  // 19328 floats = 77.3 KB -> 2 blocks/CU

// R7 structure (best measured: 92.7 us). Two kernel nodes; all cross-block
// ordering via the kernel boundary (ONE amortized L2 flush — intra-kernel
// flag+fence variants cost ~+110 us in cross-XCD writeback storms, R8/R9).
__global__ __launch_bounds__(256, 2) void fused_kernel(
    const float* __restrict__ x, const float* __restrict__ centers,
    const float* __restrict__ cw, const int* __restrict__ targets,
    float* __restrict__ tcc, float* __restrict__ cdist,
    unsigned* __restrict__ pres16, float* __restrict__ part,
    float* __restrict__ out) {
  __shared__ float sA[SAF];
  int b = blockIdx.x, tid = threadIdx.x;
  int wave = tid >> 6, lane = tid & 63;

  if (b < NC) {
    // ---- cdist + tcc for class i ----
    int i = b;
    float* ci_s = sA;
    float* wi_s = sA + ND;
    float* sred = sA + 2 * ND;
    if (i == 0 && tid == 255) out[0] = 0.f;  // d_out poisoned each launch
    for (int d = tid; d < ND; d += 256) {
      ci_s[d] = centers[i * ND + d];
      wi_s[d] = exp2f(cw[i * ND + d]);
    }
    __syncthreads();
    {
      float p = 0.f;
      for (int d = tid; d < ND; d += 256) p = fmaf(wi_s[d] * ci_s[d], ci_s[d], p);
      #pragma unroll
      for (int off = 32; off; off >>= 1) p += __shfl_xor(p, off, 64);
      if (lane == 0) sred[wave] = p;
      __syncthreads();
      if (tid == 0) tcc[i] = sred[0] + sred[1] + sred[2] + sred[3];
      __syncthreads();
    }
    float minv = 1e30f;
    for (int s = 0; s < 24; s += 4) {   // wave handles j = wave + 4*s
      float red[4];
      #pragma unroll
      for (int u = 0; u < 4; u++) {
        int j = wave + 4 * (s + u);
        float acc = 0.f;
        #pragma unroll
        for (int e = 0; e < 6; e++) {
          int d = lane + 64 * e;
          float df = ci_s[d] - centers[j * ND + d];
          acc = fmaf(wi_s[d] * df, df, acc);
        }
        red[u] = acc;
      }
      #pragma unroll
      for (int off = 32; off; off >>= 1) {
        #pragma unroll
        for (int u = 0; u < 4; u++) red[u] += __shfl_xor(red[u], off, 64);
      }
      #pragma unroll
      for (int u = 0; u < 4; u++) {
        int j = wave + 4 * (s + u);
        if (j != i) minv = fminf(minv, red[u]);
      }
    }
    {  // tail: j = wave + 96
      int j = wave + 96;
      float acc = 0.f;
      #pragma unroll
      for (int e = 0; e < 6; e++) {
        int d = lane + 64 * e;
        float df = ci_s[d] - centers[j * ND + d];
        acc = fmaf(wi_s[d] * df, df, acc);
      }
      #pragma unroll
      for (int off = 32; off; off >>= 1) acc += __shfl_xor(acc, off, 64);
      if (j != i) minv = fminf(minv, acc);
    }
    if (lane == 0) sred[wave] = minv;
    __syncthreads();
    if (tid == 0)
      cdist[i] = sqrtf(fminf(fminf(sred[0], sred[1]), fminf(sred[2], sred[3])));
  } else if (b < AUX) {
    // ---- presence (per-block local 128-bit mask) ----
    int pb = b - NC;
    unsigned* um = (unsigned*)sA;
    if (tid < 4) um[tid] = 0u;
    __syncthreads();
    int t = targets[pb * 256 + tid];
    atomicOr(&um[t >> 5], 1u << (t & 31));
    __syncthreads();
    if (tid < 4) pres16[pb * 4 + tid] = um[tid];
  } else {
    // ---- gemm: 128 samples x 128 class-slots, dims [ks*48,+48) ----
    int g = b - AUX;
    int mb = g >> 3, ks = g & 7;
    int koff = ks * KT;
    float* xs = sA;                      // [128][52]
    float* ws_t = sA + MT * XSP;         // [48][132] d-major: w
    float* as_t = ws_t + KT * CLS_PAD;   // [48][132] d-major: -2*w*c

    #pragma unroll
    for (int r = 0; r < 8; r++) {        // xs: 128 rows x 12 float4
      int idx = tid + 256 * r;
      int row = idx >> 4, slot = idx & 15;
      if (slot < 12) {
        float4 v = *(const float4*)(x + (mb * MT + row) * ND + koff + 4 * slot);
        *(float4*)&xs[row * XSP + 4 * slot] = v;
      }
    }
    for (int r = 0; r < 19; r++) {       // class data: coalesced read, d-major write
      int idx = tid + 256 * r;
      if (idx < NC * KT) {
        int k = idx / KT, d = idx - k * KT;
        float w = exp2f(cw[k * ND + koff + d]);
        float c = centers[k * ND + koff + d];
        ws_t[d * CLS_PAD + k] = w;
        as_t[d * CLS_PAD + k] = -2.f * w * c;
      }
    }
    __syncthreads();

    int cg = tid & 31, sg = tid >> 5;    // classes 4cg..4cg+3; samples sg+8m
    float acc[16][4];
    #pragma unroll
    for (int m = 0; m < 16; m++)
      #pragma unroll
      for (int u = 0; u < 4; u++) acc[m][u] = 0.f;

    #pragma unroll 1
    for (int d4 = 0; d4 < KT; d4 += 4) {
      float wv[4][4], av[4][4], xv[16][4];
      #pragma unroll
      for (int i2 = 0; i2 < 4; i2++) {
        *(float4*)&wv[i2][0] = *(const float4*)&ws_t[(d4 + i2) * CLS_PAD + 4 * cg];
        *(float4*)&av[i2][0] = *(const float4*)&as_t[(d4 + i2) * CLS_PAD + 4 * cg];
      }
      #pragma unroll
      for (int m = 0; m < 16; m++)
        *(float4*)&xv[m][0] = *(const float4*)&xs[(sg + 8 * m) * XSP + d4];
      #pragma unroll
      for (int i2 = 0; i2 < 4; i2++) {
        #pragma unroll
        for (int m = 0; m < 16; m++) {
          float xval = xv[m][i2];
          #pragma unroll
          for (int u = 0; u < 4; u++)
            acc[m][u] = fmaf(xval, fmaf(xval, wv[i2][u], av[i2][u]), acc[m][u]);
        }
      }
    }
    if (cg < 25) {  // class slots 4cg..4cg+3 all < 100
      #pragma unroll
      for (int m = 0; m < 16; m++) {
        int i = mb * MT + sg + 8 * m;
        *(float4*)&part[(ks * NB + i) * PPAD + 4 * cg] = *(float4*)&acc[m][0];
      }
    }
  }
}

// ========== Kernel 2: finish (512 blocks; 8 samples/block; 1 atomic/block) ==========
__global__ __launch_bounds__(256) void finish_kernel(
    const int* __restrict__ targets, const float* __restrict__ tcc,
    const float* __restrict__ cdist, const unsigned* __restrict__ pres16,
    const float* __restrict__ part, float* __restrict__ out) {
  __shared__ unsigned msk[4];
  __shared__ float r_an[2][2], r_ap[2][2], lsum[8];
  int tid = threadIdx.x;
  if (tid < 4) {
    unsigned m = 0;
    #pragma unroll
    for (int bb = 0; bb < 16; bb++) m |= pres16[bb * 4 + tid];
    msk[tid] = m;
  }
  int wave = tid >> 6, lane = tid & 63;
  int h = wave & 1, sl = wave >> 1;
  int k = h * 64 + lane;
  bool valid = k < NC;
  float base = valid ? tcc[k] : 0.f;
  __syncthreads();
  bool pres = valid && ((msk[k >> 5] >> (k & 31)) & 1u);

  for (int pass = 0; pass < 4; pass++) {
    int i = blockIdx.x * 8 + pass * 2 + sl;
    int ti = targets[i];
    float cand_an = 1e30f, cand_ap = 0.f;
    if (valid) {
      float d2 = base;
      #pragma unroll
      for (int s = 0; s < KS; s++) d2 += part[(s * NB + i) * PPAD + k];
      float dist = sqrtf(fmaxf(d2, 1e-12f));
      if (k == ti) cand_ap = dist;
      else if (pres) cand_an = dist;
    }
    #pragma unroll
    for (int off = 32; off; off >>= 1) {
      cand_an = fminf(cand_an, __shfl_xor(cand_an, off, 64));
      cand_ap = fmaxf(cand_ap, __shfl_xor(cand_ap, off, 64));
    }
    if (lane == 0) { r_an[sl][h] = cand_an; r_ap[sl][h] = cand_ap; }
    __syncthreads();
    if (tid < 2) {
      int isamp = blockIdx.x * 8 + pass * 2 + tid;
      float cc = cdist[targets[isamp]];
      float an = fminf(r_an[tid][0], r_an[tid][1]);
      float ap = fmaxf(r_ap[tid][0], r_ap[tid][1]);
      lsum[pass * 2 + tid] = ap + ((an >= cc) ? 0.f : cc - an);
    }
    __syncthreads();  // r_an/r_ap reused next pass
  }
  if (tid == 0) {
    float t = 0.f;
    #pragma unroll
    for (int j = 0; j < 8; j++) t += lsum[j];
    atomicAdd(out, t * (1.0f / NB));
  }
}

extern "C" void kernel_launch(void* const* d_in, const int* in_sizes, int n_in,
                              void* d_out, int out_size, void* d_ws, size_t ws_size,
                              hipStream_t stream) {
  const float* inputs  = (const float*)d_in[0];
  const int*   targets = (const int*)d_in[1];
  // d_in[2] = epoch_number (unused by the reference math)
  const float* centers = (const float*)d_in[3];
  const float* cw      = (const float*)d_in[4];
  float* out = (float*)d_out;

  float* tcc       = (float*)d_ws;                 // [128]
  float* cdist     = tcc + 128;                    // [128]
  unsigned* pres16 = (unsigned*)(cdist + 128);     // [64]
  float* part      = (float*)(pres16 + 64);        // [8*4096*104] = 13.6 MB

  fused_kernel<<<AUX + GEMM_BLOCKS, 256, 0, stream>>>(
      inputs, centers, cw, targets, tcc, cdist, pres16, part, out);
  finish_kernel<<<NB / 8, 256, 0, stream>>>(targets, tcc, cdist, pres16, part, out);
}